// Round 5
// baseline (39629.205 us; speedup 1.0000x reference)
//
#include <hip/hip_runtime.h>
#include <hip/hip_bf16.h>

// HyperLSTM + MDN decoder. Dims fixed by the reference.
// World model (R5, evidence-driven):
//   - inputs  FLOAT32  (R3->R4: reading as f32 eliminated NaN)
//   - output  FLOAT32  (R4: constant-1.0 mw region read back wrong in a way
//     exactly explained by f32 readout of bf16-packed data)
#define MM    20
#define LATENT 128
#define IN_DIM 133
#define HDIM  1024
#define HY    256
#define FF    64
#define NSEQ  128
#define BB    64
#define OUT_DIM 123   // 6*M+3

// Persistent state in __device__ globals (valid regardless of ws_size; fully
// rewritten every call -> graph-replay safe).
__device__ float g_h  [BB * HDIM];
__device__ float g_c  [BB * HDIM];
__device__ float g_hh [BB * HY];
__device__ float g_ch [BB * HY];
__device__ float g_hWh[BB * 4 * HDIM];

__device__ __forceinline__ float sigf(float x) { return 1.0f / (1.0f + expf(-x)); }

// ---------------------------------------------------------------------------
// init: s0 = tanh(z @ fc_in_w + fc_in_b); split into h0,c0,hh0,ch0
// grid 64, block 256
// ---------------------------------------------------------------------------
__global__ __launch_bounds__(256) void init_kernel(
    const float* __restrict__ z, const float* __restrict__ fc_in_w,
    const float* __restrict__ fc_in_b)
{
    int b = blockIdx.x, tid = threadIdx.x;
    __shared__ float zs[LATENT];
    if (tid < LATENT) zs[tid] = z[b * LATENT + tid];
    __syncthreads();
    for (int j = tid; j < 2560; j += 256) {
        float acc = fc_in_b[j];
        #pragma unroll 4
        for (int k = 0; k < LATENT; k++) acc += zs[k] * fc_in_w[k * 2560 + j];
        float s = tanhf(acc);
        if      (j < 1024) g_h [b * 1024 + j]          = s;
        else if (j < 2048) g_c [b * 1024 + (j - 1024)] = s;
        else if (j < 2304) g_hh[b * 256  + (j - 2048)] = s;
        else               g_ch[b * 256  + (j - 2304)] = s;
    }
}

// ---------------------------------------------------------------------------
// step A (block 256, grid 192):
//  blocks   0..63  : hyper gates g=[x_t,h]@Wxh_hy + hh@Whh_hy + b_hy; update hh,ch
//  blocks  64..127 : g_hWh = h @ Wh, b-tiled by 4
//  blocks 128..191 : projection + MDN output for step t-1 (reads g_h from B(t-1))
// Tail launch with t==NSEQ runs only the proj role (for t=127).
// ---------------------------------------------------------------------------
__global__ __launch_bounds__(256) void step_kernel_A(
    const float* __restrict__ strokes,
    const float* __restrict__ Wxh_hy, const float* __restrict__ Whh_hy,
    const float* __restrict__ b_hy,   const float* __restrict__ Wh,
    const float* __restrict__ fc_proj_w, const float* __restrict__ fc_proj_b,
    float* __restrict__ out, int t)
{
    int tid = threadIdx.x;
    if (blockIdx.x < 64) {
        if (t >= NSEQ) return;
        int b = blockIdx.x;
        __shared__ float xs[IN_DIM];
        __shared__ float hs[HDIM];
        __shared__ float hhs[HY];
        __shared__ float gs[1024];
        for (int i = tid; i < IN_DIM; i += 256)
            xs[i] = strokes[(t * BB + b) * IN_DIM + i];
        for (int i = tid; i < HDIM; i += 256) hs[i] = g_h[b * HDIM + i];
        hhs[tid] = g_hh[b * HY + tid];
        __syncthreads();

        int j0 = tid * 4;
        float4 bh = *(const float4*)(b_hy + j0);
        float a0 = bh.x, a1 = bh.y, a2 = bh.z, a3 = bh.w;
        for (int k = 0; k < IN_DIM; k++) {
            float xv = xs[k];
            float4 w = *(const float4*)(Wxh_hy + k * 1024 + j0);
            a0 += xv * w.x; a1 += xv * w.y; a2 += xv * w.z; a3 += xv * w.w;
        }
        #pragma unroll 4
        for (int k = 0; k < HDIM; k++) {
            float hv = hs[k];
            float4 w = *(const float4*)(Wxh_hy + (IN_DIM + k) * 1024 + j0);
            a0 += hv * w.x; a1 += hv * w.y; a2 += hv * w.z; a3 += hv * w.w;
        }
        #pragma unroll 4
        for (int k = 0; k < HY; k++) {
            float hv = hhs[k];
            float4 w = *(const float4*)(Whh_hy + k * 1024 + j0);
            a0 += hv * w.x; a1 += hv * w.y; a2 += hv * w.z; a3 += hv * w.w;
        }
        gs[j0] = a0; gs[j0 + 1] = a1; gs[j0 + 2] = a2; gs[j0 + 3] = a3;
        __syncthreads();

        float gi = gs[tid], gf = gs[256 + tid], gg = gs[512 + tid], go = gs[768 + tid];
        float chv = g_ch[b * HY + tid];
        chv = sigf(gf) * chv + sigf(gi) * tanhf(gg);
        float hhv = sigf(go) * tanhf(chv);
        g_ch[b * HY + tid] = chv;
        g_hh[b * HY + tid] = hhv;
    } else if (blockIdx.x < 128) {
        if (t >= NSEQ) return;
        int bb = blockIdx.x - 64;
        int chunk = bb & 3, bs = (bb >> 2) * 4;   // 4 batch rows per block
        __shared__ float hs2[4][HDIM];
        for (int i = tid; i < 4 * HDIM; i += 256)
            hs2[i >> 10][i & 1023] = g_h[(bs + (i >> 10)) * HDIM + (i & 1023)];
        __syncthreads();
        int j0 = chunk * 1024 + tid * 4;
        float acc[4][4];
        #pragma unroll
        for (int bi = 0; bi < 4; bi++)
            acc[bi][0] = acc[bi][1] = acc[bi][2] = acc[bi][3] = 0.f;
        #pragma unroll 2
        for (int k = 0; k < HDIM; k++) {
            float4 w = *(const float4*)(Wh + k * 4096 + j0);
            #pragma unroll
            for (int bi = 0; bi < 4; bi++) {
                float f = hs2[bi][k];
                acc[bi][0] += f * w.x; acc[bi][1] += f * w.y;
                acc[bi][2] += f * w.z; acc[bi][3] += f * w.w;
            }
        }
        #pragma unroll
        for (int bi = 0; bi < 4; bi++) {
            float* o = g_hWh + (bs + bi) * 4096 + j0;
            o[0] = acc[bi][0]; o[1] = acc[bi][1];
            o[2] = acc[bi][2]; o[3] = acc[bi][3];
        }
    } else {
        // projection for step tp = t-1 (g_h currently holds h after step t-1)
        if (t < 1) return;
        int tp = t - 1;
        int b = blockIdx.x - 128;
        __shared__ float hsr[HDIM];
        __shared__ float pend[3];
        for (int i = tid; i < HDIM; i += 256) hsr[i] = g_h[b * HDIM + i];
        __syncthreads();
        if (tid < OUT_DIM) {
            float acc = fc_proj_b[tid];
            #pragma unroll 4
            for (int k = 0; k < HDIM; k++) acc += hsr[k] * fc_proj_w[k * OUT_DIM + tid];
            if (tid < 120) {
                int m = tid / 6, jj = tid - m * 6;
                int oidx = tp * (MM * BB) + m * BB + b;
                if      (jj == 0) out[0      + oidx] = 1.0f;
                else if (jj == 1) out[163840 + oidx] = acc;
                else if (jj == 2) out[327680 + oidx] = acc;
                else if (jj == 3) out[491520 + oidx] = expf(acc);
                else if (jj == 4) out[655360 + oidx] = expf(acc);
                else              out[819200 + oidx] = tanhf(acc);
            } else {
                pend[tid - 120] = acc;
            }
        }
        __syncthreads();
        if (tid < 3) {
            float v0 = pend[0], v1 = pend[1], v2 = pend[2];
            float mx = fmaxf(v0, fmaxf(v1, v2));
            float e0 = expf(v0 - mx), e1 = expf(v1 - mx), e2 = expf(v2 - mx);
            float s = e0 + e1 + e2;
            float e = (tid == 0) ? e0 : ((tid == 1) ? e1 : e2);
            out[983040 + tp * (BB * 3) + b * 3 + tid] = e / s;
        }
    }
}

// ---------------------------------------------------------------------------
// step B: z = hh@Wz* (+bias), s* = einsum(z, D*), pre = sx*(x@Wx)+sh*hWh+sb+b0,
//         main LSTM update of c,h (in place).
// grid 256 = b*4 + r ; thread tid handles hidx = r*256+tid
// ---------------------------------------------------------------------------
__global__ __launch_bounds__(256) void step_kernel_B(
    const float* __restrict__ strokes,
    const float* __restrict__ Wzx, const float* __restrict__ bzx,
    const float* __restrict__ Wzh, const float* __restrict__ bzh,
    const float* __restrict__ Wzb,
    const float* __restrict__ Dx, const float* __restrict__ Dh,
    const float* __restrict__ Db,
    const float* __restrict__ Wx, const float* __restrict__ b0, int t)
{
    int tid = threadIdx.x;
    int b = blockIdx.x >> 2, r = blockIdx.x & 3;
    __shared__ float zxs[HY], zhs[HY], zbs[HY], hhs[HY], xs[IN_DIM];
    hhs[tid] = g_hh[b * HY + tid];
    for (int i = tid; i < IN_DIM; i += 256)
        xs[i] = strokes[(t * BB + b) * IN_DIM + i];
    __syncthreads();
    {
        float ax = bzx[tid];
        float ah = bzh[tid];
        float ab = 0.f;
        #pragma unroll 4
        for (int k = 0; k < HY; k++) {
            float hv = hhs[k];
            ax += hv * Wzx[k * 256 + tid];
            ah += hv * Wzh[k * 256 + tid];
            ab += hv * Wzb[k * 256 + tid];
        }
        zxs[tid] = ax; zhs[tid] = ah; zbs[tid] = ab;
    }
    __syncthreads();

    int hidx = r * 256 + tid;
    float pre[4];
    #pragma unroll
    for (int g = 0; g < 4; g++) {
        float sx = 0.f, sh = 0.f, sb = 0.f;
        int base = g * 64;
        #pragma unroll 4
        for (int f = 0; f < FF; f++) {
            int di = (base + f) * 1024 + hidx;
            sx += zxs[base + f] * Dx[di];
            sh += zhs[base + f] * Dh[di];
            sb += zbs[base + f] * Db[di];
        }
        float xwx = 0.f;
        for (int k = 0; k < IN_DIM; k++)
            xwx += xs[k] * Wx[k * 4096 + g * 1024 + hidx];
        pre[g] = sx * xwx + sh * g_hWh[b * 4096 + g * 1024 + hidx] + sb
               + b0[g * 1024 + hidx];
    }
    float cv = g_c[b * HDIM + hidx];
    cv = sigf(pre[1]) * cv + sigf(pre[0]) * tanhf(pre[2]);
    float hv = sigf(pre[3]) * tanhf(cv);
    g_c[b * HDIM + hidx] = cv;
    g_h[b * HDIM + hidx] = hv;
}

// ---------------------------------------------------------------------------
extern "C" void kernel_launch(void* const* d_in, const int* in_sizes, int n_in,
                              void* d_out, int out_size, void* d_ws, size_t ws_size,
                              hipStream_t stream)
{
    const float* z         = (const float*)d_in[0];
    const float* strokes   = (const float*)d_in[1];
    const float* fc_in_w   = (const float*)d_in[2];
    const float* fc_in_b   = (const float*)d_in[3];
    const float* fc_proj_w = (const float*)d_in[4];
    const float* fc_proj_b = (const float*)d_in[5];
    const float* Wx        = (const float*)d_in[6];
    const float* Wh        = (const float*)d_in[7];
    const float* b0        = (const float*)d_in[8];
    const float* Wxh_hy    = (const float*)d_in[9];
    const float* Whh_hy    = (const float*)d_in[10];
    const float* b_hy      = (const float*)d_in[11];
    const float* Wzx       = (const float*)d_in[12];
    const float* bzx       = (const float*)d_in[13];
    const float* Wzh       = (const float*)d_in[14];
    const float* bzh       = (const float*)d_in[15];
    const float* Wzb       = (const float*)d_in[16];
    const float* Dx        = (const float*)d_in[17];
    const float* Dh        = (const float*)d_in[18];
    const float* Db        = (const float*)d_in[19];
    (void)d_ws; (void)ws_size;
    float* out = (float*)d_out;

    init_kernel<<<64, 256, 0, stream>>>(z, fc_in_w, fc_in_b);
    for (int t = 0; t < NSEQ; t++) {
        step_kernel_A<<<192, 256, 0, stream>>>(strokes, Wxh_hy, Whh_hy, b_hy, Wh,
                                               fc_proj_w, fc_proj_b, out, t);
        step_kernel_B<<<256, 256, 0, stream>>>(strokes, Wzx, bzx, Wzh, bzh, Wzb,
                                               Dx, Dh, Db, Wx, b0, t);
    }
    // tail: projection for t = 127 (proj role only)
    step_kernel_A<<<192, 256, 0, stream>>>(strokes, Wxh_hy, Whh_hy, b_hy, Wh,
                                           fc_proj_w, fc_proj_b, out, NSEQ);
}

// Round 6
// 28096.924 us; speedup vs baseline: 1.4104x; 1.4104x over previous
//
#include <hip/hip_runtime.h>

// HyperLSTM + MDN decoder — f32 in, f32 out (verified R5, absmax 7.8e-3).
// R6: full-chip parallel phase kernels (P1/P2/P3 per step) to fix the
// latency-bound 2.8% VALUBusy / 200+us-per-step baseline.
#define MM     20
#define LATENT 128
#define IN_DIM 133
#define HD     1024
#define HD4    4096
#define HY     256
#define FF     64
#define NSEQ   128
#define BB     64
#define OUT_DIM 123   // 6*M+3

// Persistent state + intermediates in __device__ globals (d_ws size unknown).
__device__ float g_h  [BB * HD];
__device__ float g_c  [BB * HD];
__device__ float g_hh [BB * HY];
__device__ float g_ch [BB * HY];
__device__ float g_g  [BB * HD];        // hyper pre-gates
__device__ float g_hWh[BB * HD4];
__device__ float g_xWx[BB * HD4];
__device__ float g_z  [BB * 3 * HY];    // zx|zh|zb per b, each [4][64] flat

__device__ __forceinline__ float sigf(float x) { return 1.0f / (1.0f + expf(-x)); }

// ---------------------------------------------------------------------------
// init: s0 = tanh(z @ fc_in_w + fc_in_b) -> h0,c0,hh0,ch0.  grid 64 x 256
// ---------------------------------------------------------------------------
__global__ __launch_bounds__(256) void init_kernel(
    const float* __restrict__ z, const float* __restrict__ fc_in_w,
    const float* __restrict__ fc_in_b)
{
    int b = blockIdx.x, tid = threadIdx.x;
    __shared__ float zs[LATENT];
    if (tid < LATENT) zs[tid] = z[b * LATENT + tid];
    __syncthreads();
    for (int j = tid; j < 2560; j += 256) {
        float acc = fc_in_b[j];
        #pragma unroll 4
        for (int k = 0; k < LATENT; k++) acc += zs[k] * fc_in_w[k * 2560 + j];
        float s = tanhf(acc);
        if      (j < 1024) g_h [b * 1024 + j]          = s;
        else if (j < 2048) g_c [b * 1024 + (j - 1024)] = s;
        else if (j < 2304) g_hh[b * 256  + (j - 2048)] = s;
        else               g_ch[b * 256  + (j - 2304)] = s;
    }
}

// ---------------------------------------------------------------------------
// P1 (grid 256 x 512): block = (s = blk&15 col-slice, u = blk>>4 b-group of 4)
//   threads 0..255 : hWh (256 cols x 4 b, k=1024) + xWx (k=133)
//   threads 256..511: hyper gates (64 cols x 4 b, k=1389)
//   blocks s==15   : also projection+MDN for step t-1 (h staged = h_{t-1})
// Tail launch t==NSEQ: proj-only for t=127.
// ---------------------------------------------------------------------------
__global__ __launch_bounds__(512) void p1_kernel(
    const float* __restrict__ strokes,
    const float* __restrict__ Wxh_hy, const float* __restrict__ Whh_hy,
    const float* __restrict__ b_hy,   const float* __restrict__ Wh,
    const float* __restrict__ Wx,
    const float* __restrict__ fc_proj_w, const float* __restrict__ fc_proj_b,
    float* __restrict__ out, int t)
{
    int blk = blockIdx.x, tid = threadIdx.x;
    int s = blk & 15;         // 16 col-slices
    int b0 = (blk >> 4) * 4;  // 16 b-groups x 4 rows
    __shared__ float hs[4][HD];
    __shared__ float xs[4][IN_DIM];
    __shared__ float hhs[4][HY];
    __shared__ float pend[4][3];

    for (int i = tid; i < 4 * HD; i += 512)
        hs[i >> 10][i & 1023] = g_h[(b0 + (i >> 10)) * HD + (i & 1023)];
    if (t < NSEQ) {
        for (int i = tid; i < 4 * IN_DIM; i += 512)
            xs[i / IN_DIM][i % IN_DIM] =
                strokes[(t * BB + b0 + i / IN_DIM) * IN_DIM + (i % IN_DIM)];
        for (int i = tid; i < 4 * HY; i += 512)
            hhs[i >> 8][i & 255] = g_hh[(b0 + (i >> 8)) * HY + (i & 255)];
    }
    __syncthreads();

    if (t < NSEQ) {
        if (tid < 256) {
            int c = s * 256 + tid;
            float a0 = 0.f, a1 = 0.f, a2 = 0.f, a3 = 0.f;
            #pragma unroll 4
            for (int k = 0; k < HD; k++) {
                float w = Wh[k * HD4 + c];
                a0 += hs[0][k] * w; a1 += hs[1][k] * w;
                a2 += hs[2][k] * w; a3 += hs[3][k] * w;
            }
            g_hWh[(b0 + 0) * HD4 + c] = a0;
            g_hWh[(b0 + 1) * HD4 + c] = a1;
            g_hWh[(b0 + 2) * HD4 + c] = a2;
            g_hWh[(b0 + 3) * HD4 + c] = a3;
            a0 = a1 = a2 = a3 = 0.f;
            for (int k = 0; k < IN_DIM; k++) {
                float w = Wx[k * HD4 + c];
                a0 += xs[0][k] * w; a1 += xs[1][k] * w;
                a2 += xs[2][k] * w; a3 += xs[3][k] * w;
            }
            g_xWx[(b0 + 0) * HD4 + c] = a0;
            g_xWx[(b0 + 1) * HD4 + c] = a1;
            g_xWx[(b0 + 2) * HD4 + c] = a2;
            g_xWx[(b0 + 3) * HD4 + c] = a3;
        } else {
            int j = tid - 256;
            int gc = s * 64 + (j & 63);   // gate col (of 1024)
            int bi = j >> 6;              // wave-uniform
            float acc = b_hy[gc];
            for (int k = 0; k < IN_DIM; k++)
                acc += xs[bi][k] * Wxh_hy[k * HD + gc];
            #pragma unroll 4
            for (int k = 0; k < HD; k++)
                acc += hs[bi][k] * Wxh_hy[(IN_DIM + k) * HD + gc];
            #pragma unroll 4
            for (int k = 0; k < HY; k++)
                acc += hhs[bi][k] * Whh_hy[k * HD + gc];
            g_g[(b0 + bi) * HD + gc] = acc;
        }
    }

    if (s == 15 && t > 0) {          // projection for tp = t-1 (hs = h_{t-1})
        int tp = t - 1;
        if (tid < 4 * OUT_DIM) {
            int bi = tid / OUT_DIM, col = tid % OUT_DIM;
            float acc = fc_proj_b[col];
            #pragma unroll 4
            for (int k = 0; k < HD; k++)
                acc += hs[bi][k] * fc_proj_w[k * OUT_DIM + col];
            int b = b0 + bi;
            if (col < 120) {
                int m = col / 6, jj = col - m * 6;
                int oidx = tp * (MM * BB) + m * BB + b;
                if      (jj == 0) out[0      + oidx] = 1.0f;
                else if (jj == 1) out[163840 + oidx] = acc;
                else if (jj == 2) out[327680 + oidx] = acc;
                else if (jj == 3) out[491520 + oidx] = expf(acc);
                else if (jj == 4) out[655360 + oidx] = expf(acc);
                else              out[819200 + oidx] = tanhf(acc);
            } else {
                pend[bi][col - 120] = acc;
            }
        }
        __syncthreads();
        if (tid < 12) {
            int bi = tid / 3, e = tid % 3;
            float v0 = pend[bi][0], v1 = pend[bi][1], v2 = pend[bi][2];
            float mx = fmaxf(v0, fmaxf(v1, v2));
            float e0 = expf(v0 - mx), e1 = expf(v1 - mx), e2 = expf(v2 - mx);
            float ssum = e0 + e1 + e2;
            float ev = (e == 0) ? e0 : ((e == 1) ? e1 : e2);
            out[983040 + tp * (BB * 3) + (b0 + bi) * 3 + e] = ev / ssum;
        }
    }
}

// ---------------------------------------------------------------------------
// P2 (grid 64 x 256): hyper-LSTM update (hh,ch) + z = hh@Wz* (+bias), once.
// ---------------------------------------------------------------------------
__global__ __launch_bounds__(256) void p2_kernel(
    const float* __restrict__ Wzx, const float* __restrict__ bzx,
    const float* __restrict__ Wzh, const float* __restrict__ bzh,
    const float* __restrict__ Wzb)
{
    int b = blockIdx.x, tid = threadIdx.x;
    __shared__ float hhs[HY];
    float gi = g_g[b * HD + tid],       gf = g_g[b * HD + 256 + tid];
    float gg = g_g[b * HD + 512 + tid], go = g_g[b * HD + 768 + tid];
    float chv = g_ch[b * HY + tid];
    chv = sigf(gf) * chv + sigf(gi) * tanhf(gg);
    float hhv = sigf(go) * tanhf(chv);
    g_ch[b * HY + tid] = chv;
    g_hh[b * HY + tid] = hhv;
    hhs[tid] = hhv;
    __syncthreads();
    for (int o = tid; o < 3 * HY; o += 256) {
        int ten = o >> 8, oo = o & 255;
        const float* W = (ten == 0) ? Wzx : (ten == 1) ? Wzh : Wzb;
        float acc = (ten == 0) ? bzx[oo] : (ten == 1) ? bzh[oo] : 0.f;
        #pragma unroll 4
        for (int k = 0; k < HY; k++) acc += hhs[k] * W[k * HY + oo];
        g_z[(b * 3 + ten) * HY + oo] = acc;
    }
}

// ---------------------------------------------------------------------------
// P3 (grid 256 x 512): block = (b = blk>>2, h-slice = blk&3 of 256).
//   einsum s* from LDS-staged z, combine with xWx/hWh/b0, main LSTM update.
// ---------------------------------------------------------------------------
__global__ __launch_bounds__(512) void p3_kernel(
    const float* __restrict__ Dx, const float* __restrict__ Dh,
    const float* __restrict__ Db, const float* __restrict__ b0w)
{
    int blk = blockIdx.x, tid = threadIdx.x;
    int b = blk >> 2, sl = blk & 3;
    __shared__ float zl[3][HY];
    __shared__ float pre_l[4][HY];
    for (int i = tid; i < 3 * HY; i += 512) zl[i >> 8][i & 255] = g_z[b * 3 * HY + i];
    __syncthreads();
    int hi_l = tid & 255, gp = tid >> 8;
    int hi = sl * 256 + hi_l;
    #pragma unroll
    for (int gsub = 0; gsub < 2; gsub++) {
        int g = gp * 2 + gsub;
        float sx = 0.f, sh = 0.f, sb = 0.f;
        #pragma unroll 4
        for (int f = 0; f < FF; f++) {
            int zi = g * 64 + f;
            int di = zi * HD + hi;
            sx += zl[0][zi] * Dx[di];
            sh += zl[1][zi] * Dh[di];
            sb += zl[2][zi] * Db[di];
        }
        float pre = sx * g_xWx[b * HD4 + g * HD + hi]
                  + sh * g_hWh[b * HD4 + g * HD + hi]
                  + sb + b0w[g * HD + hi];
        pre_l[g][hi_l] = pre;
    }
    __syncthreads();
    if (tid < 256) {
        int h_abs = b * HD + sl * 256 + tid;
        float cv = g_c[h_abs];
        float nc = sigf(pre_l[1][tid]) * cv + sigf(pre_l[0][tid]) * tanhf(pre_l[2][tid]);
        float nh = sigf(pre_l[3][tid]) * tanhf(nc);
        g_c[h_abs] = nc;
        g_h[h_abs] = nh;
    }
}

// ---------------------------------------------------------------------------
extern "C" void kernel_launch(void* const* d_in, const int* in_sizes, int n_in,
                              void* d_out, int out_size, void* d_ws, size_t ws_size,
                              hipStream_t stream)
{
    const float* z         = (const float*)d_in[0];
    const float* strokes   = (const float*)d_in[1];
    const float* fc_in_w   = (const float*)d_in[2];
    const float* fc_in_b   = (const float*)d_in[3];
    const float* fc_proj_w = (const float*)d_in[4];
    const float* fc_proj_b = (const float*)d_in[5];
    const float* Wx        = (const float*)d_in[6];
    const float* Wh        = (const float*)d_in[7];
    const float* b0w       = (const float*)d_in[8];
    const float* Wxh_hy    = (const float*)d_in[9];
    const float* Whh_hy    = (const float*)d_in[10];
    const float* b_hy      = (const float*)d_in[11];
    const float* Wzx       = (const float*)d_in[12];
    const float* bzx       = (const float*)d_in[13];
    const float* Wzh       = (const float*)d_in[14];
    const float* bzh       = (const float*)d_in[15];
    const float* Wzb       = (const float*)d_in[16];
    const float* Dx        = (const float*)d_in[17];
    const float* Dh        = (const float*)d_in[18];
    const float* Db        = (const float*)d_in[19];
    (void)d_ws; (void)ws_size;
    float* out = (float*)d_out;

    init_kernel<<<64, 256, 0, stream>>>(z, fc_in_w, fc_in_b);
    for (int t = 0; t < NSEQ; t++) {
        p1_kernel<<<256, 512, 0, stream>>>(strokes, Wxh_hy, Whh_hy, b_hy, Wh, Wx,
                                           fc_proj_w, fc_proj_b, out, t);
        p2_kernel<<<64, 256, 0, stream>>>(Wzx, bzx, Wzh, bzh, Wzb);
        p3_kernel<<<256, 512, 0, stream>>>(Dx, Dh, Db, b0w);
    }
    // tail: projection for t = 127
    p1_kernel<<<256, 512, 0, stream>>>(strokes, Wxh_hy, Whh_hy, b_hy, Wh, Wx,
                                       fc_proj_w, fc_proj_b, out, NSEQ);
}